// Round 1
// baseline (1861.798 us; speedup 1.0000x reference)
//
#include <hip/hip_runtime.h>

#define RPB  64     // rows per block
#define NTHR 512    // 8 waves

typedef _Float16 f16;
typedef _Float16 f16x2 __attribute__((ext_vector_type(2)));

__device__ __forceinline__ float fdot2f(f16x2 a, f16x2 b, float c) {
#if __has_builtin(__builtin_amdgcn_fdot2)
  return __builtin_amdgcn_fdot2(a, b, c, false);
#else
  return c + (float)a[0] * (float)b[0] + (float)a[1] * (float)b[1];
#endif
}

// load a 128-float weight row from global and pack to 64 f16x2 regs
__device__ __forceinline__ void load_row128(const float* __restrict__ p, f16x2* wr) {
  const float4* p4 = (const float4*)p;
#pragma unroll
  for (int q = 0; q < 32; ++q) {
    float4 f = p4[q];
    wr[2*q]     = (f16x2){(f16)f.x, (f16)f.y};
    wr[2*q + 1] = (f16x2){(f16)f.z, (f16)f.w};
  }
}

__global__ __launch_bounds__(NTHR, 1)
void adain_fused(const float* __restrict__ x,   const float* __restrict__ meta,
                 const float* __restrict__ mw1, const float* __restrict__ mb1,
                 const float* __restrict__ mw2, const float* __restrict__ mb2,
                 const float* __restrict__ mw3, const float* __restrict__ mb3,
                 const float* __restrict__ w1,  const float* __restrict__ b1,
                 const float* __restrict__ w2,  const float* __restrict__ b2,
                 const float* __restrict__ w3,  const float* __restrict__ b3,
                 const float* __restrict__ w4,  const float* __restrict__ b4,
                 const float* __restrict__ w5,  const float* __restrict__ b5,
                 float* __restrict__ out)
{
  __shared__ float sMeta[RPB][16];    // 4 KB
  __shared__ f16   sH1[RPB][64];      // 8 KB
  __shared__ f16   sH2[RPB][128];     // 16 KB
  __shared__ float sPre[RPB][130];    // 33.3 KB  pre-adain activations (fp32 for stats)
  __shared__ f16   sY[RPB][130];      // 16.6 KB  post-adain y (f16 matvec input)
  __shared__ f16   sS[RPB][258];      // 33 KB    current style chunk (scale,bias interleaved)
  __shared__ float sX[RPB];

  const int t  = threadIdx.x;
  const int r0 = blockIdx.x * RPB;

  // ---- stage metadata + x ----
  for (int i = t; i < RPB * 16; i += NTHR)
    sMeta[i >> 4][i & 15] = meta[(size_t)r0 * 16 + i];
  if (t < RPB) sX[t] = x[r0 + t];
  __syncthreads();

  // ---- h1 = relu(meta @ mw1.T + mb1) : (64,16)->(64,64) ----
  {
    const int j = t & 63, rg = t >> 6;           // 8 rows each
    float wr[16];
    const float4* p4 = (const float4*)(mw1 + j * 16);
#pragma unroll
    for (int q = 0; q < 4; ++q) {
      float4 f = p4[q];
      wr[4*q] = f.x; wr[4*q+1] = f.y; wr[4*q+2] = f.z; wr[4*q+3] = f.w;
    }
    const float bj = mb1[j];
#pragma unroll 1
    for (int rr = 0; rr < 8; ++rr) {
      const int r = rg * 8 + rr;
      float acc = bj;
#pragma unroll
      for (int k = 0; k < 16; ++k) acc += wr[k] * sMeta[r][k];
      sH1[r][j] = (f16)fmaxf(acc, 0.0f);
    }
  }
  __syncthreads();

  // ---- h2 = relu(h1 @ mw2.T + mb2) : (64,64)->(64,128) ----
  {
    const int c = t & 127, rq = t >> 7;          // 16 rows each
    f16x2 wr[32];
    const float4* p4 = (const float4*)(mw2 + c * 64);
#pragma unroll
    for (int q = 0; q < 16; ++q) {
      float4 f = p4[q];
      wr[2*q]     = (f16x2){(f16)f.x, (f16)f.y};
      wr[2*q + 1] = (f16x2){(f16)f.z, (f16)f.w};
    }
    const float bc = mb2[c];
#pragma unroll 1
    for (int rb = 0; rb < 4; ++rb) {
      const int r = rq * 16 + rb * 4;
      float a0 = bc, a1 = bc, a2 = bc, a3 = bc;
#pragma unroll
      for (int kk = 0; kk < 32; ++kk) {
        a0 = fdot2f(wr[kk], *(const f16x2*)&sH1[r + 0][2*kk], a0);
        a1 = fdot2f(wr[kk], *(const f16x2*)&sH1[r + 1][2*kk], a1);
        a2 = fdot2f(wr[kk], *(const f16x2*)&sH1[r + 2][2*kk], a2);
        a3 = fdot2f(wr[kk], *(const f16x2*)&sH1[r + 3][2*kk], a3);
      }
      sH2[r + 0][c] = (f16)fmaxf(a0, 0.0f);
      sH2[r + 1][c] = (f16)fmaxf(a1, 0.0f);
      sH2[r + 2][c] = (f16)fmaxf(a2, 0.0f);
      sH2[r + 3][c] = (f16)fmaxf(a3, 0.0f);
    }
  }
  __syncthreads();

  // ---- 4 AdaIN layers ----
#pragma unroll 1
  for (int l = 0; l < 4; ++l) {
    // (a) style chunk l: sS[r][j] = h2[r] . mw3[256l+j] + mb3[256l+j]
    {
      const int j = t & 255, rh = t >> 8;        // rows rh*32 .. +31
      f16x2 wr[64];
      load_row128(mw3 + (size_t)(l * 256 + j) * 128, wr);
      const float bj = mb3[l * 256 + j];
#pragma unroll 1
      for (int rb = 0; rb < 8; ++rb) {
        const int r = rh * 32 + rb * 4;
        float a0 = bj, a1 = bj, a2 = bj, a3 = bj;
#pragma unroll
        for (int kk = 0; kk < 64; ++kk) {
          a0 = fdot2f(wr[kk], *(const f16x2*)&sH2[r + 0][2*kk], a0);
          a1 = fdot2f(wr[kk], *(const f16x2*)&sH2[r + 1][2*kk], a1);
          a2 = fdot2f(wr[kk], *(const f16x2*)&sH2[r + 2][2*kk], a2);
          a3 = fdot2f(wr[kk], *(const f16x2*)&sH2[r + 3][2*kk], a3);
        }
        sS[r + 0][j] = (f16)a0;
        sS[r + 1][j] = (f16)a1;
        sS[r + 2][j] = (f16)a2;
        sS[r + 3][j] = (f16)a3;
      }
    }

    // (b) pre-activation for this layer -> sPre
    if (l == 0) {
      const int c = t & 127, rq = t >> 7;
      const float w1c = w1[c], b1c = b1[c];
#pragma unroll 1
      for (int rr = 0; rr < 16; ++rr) {
        const int r = rq * 16 + rr;
        sPre[r][c] = sX[r] * w1c + b1c;
      }
    } else {
      const float* W  = (l == 1) ? w2 : (l == 2) ? w3 : w4;
      const float* Bv = (l == 1) ? b2 : (l == 2) ? b3 : b4;
      const int c = t & 127, rq = t >> 7;
      f16x2 wr[64];
      load_row128(W + (size_t)c * 128, wr);
      const float bc = Bv[c];
#pragma unroll 1
      for (int rb = 0; rb < 4; ++rb) {
        const int r = rq * 16 + rb * 4;
        float a0 = bc, a1 = bc, a2 = bc, a3 = bc;
#pragma unroll
        for (int kk = 0; kk < 64; ++kk) {
          a0 = fdot2f(wr[kk], *(const f16x2*)&sY[r + 0][2*kk], a0);
          a1 = fdot2f(wr[kk], *(const f16x2*)&sY[r + 1][2*kk], a1);
          a2 = fdot2f(wr[kk], *(const f16x2*)&sY[r + 2][2*kk], a2);
          a3 = fdot2f(wr[kk], *(const f16x2*)&sY[r + 3][2*kk], a3);
        }
        sPre[r + 0][c] = a0;
        sPre[r + 1][c] = a1;
        sPre[r + 2][c] = a2;
        sPre[r + 3][c] = a3;
      }
    }
    __syncthreads();

    // (c) adain + lrelu : sPre + sS -> sY
    {
      const int r = t >> 3, j = t & 7;           // 8 lanes per row
      float s = 0.0f;
#pragma unroll
      for (int i = 0; i < 16; ++i) s += sPre[r][j + 8 * i];
      s += __shfl_xor(s, 1, 8);
      s += __shfl_xor(s, 2, 8);
      s += __shfl_xor(s, 4, 8);
      const float mu = s * (1.0f / 128.0f);

      float v = 0.0f;
#pragma unroll
      for (int i = 0; i < 16; ++i) {
        const float d = sPre[r][j + 8 * i] - mu;
        v += d * d;
      }
      v += __shfl_xor(v, 1, 8);
      v += __shfl_xor(v, 2, 8);
      v += __shfl_xor(v, 4, 8);
      const float sigma = sqrtf(v * (1.0f / 127.0f)) + 1e-6f;
      const float rs = 1.0f / sigma;

#pragma unroll
      for (int i = 0; i < 16; ++i) {
        const int k = j + 8 * i;
        const float scale = (float)sS[r][2 * k];
        const float bias  = (float)sS[r][2 * k + 1];
        float val = scale * (sPre[r][k] - mu) * rs + bias;
        val = (val > 0.0f) ? val : 0.01f * val;
        sY[r][k] = (f16)val;
      }
    }
    __syncthreads();
  }

  // ---- out = lrelu(y @ w5.T + b5) ----
  {
    const int r = t >> 3, j = t & 7;
    float s = 0.0f;
#pragma unroll
    for (int i = 0; i < 16; ++i) {
      const int k = j + 8 * i;
      s += (float)sY[r][k] * w5[k];
    }
    s += __shfl_xor(s, 1, 8);
    s += __shfl_xor(s, 2, 8);
    s += __shfl_xor(s, 4, 8);
    if (j == 0) {
      float val = s + b5[0];
      val = (val > 0.0f) ? val : 0.01f * val;
      out[r0 + r] = val;
    }
  }
}

extern "C" void kernel_launch(void* const* d_in, const int* in_sizes, int n_in,
                              void* d_out, int out_size, void* d_ws, size_t ws_size,
                              hipStream_t stream) {
  const float* x    = (const float*)d_in[0];
  const float* meta = (const float*)d_in[1];
  const float* mw1  = (const float*)d_in[2];
  const float* mb1  = (const float*)d_in[3];
  const float* mw2  = (const float*)d_in[4];
  const float* mb2  = (const float*)d_in[5];
  const float* mw3  = (const float*)d_in[6];
  const float* mb3  = (const float*)d_in[7];
  const float* w1   = (const float*)d_in[8];
  const float* b1   = (const float*)d_in[9];
  const float* w2   = (const float*)d_in[10];
  const float* b2   = (const float*)d_in[11];
  const float* w3   = (const float*)d_in[12];
  const float* b3   = (const float*)d_in[13];
  const float* w4   = (const float*)d_in[14];
  const float* b4   = (const float*)d_in[15];
  const float* w5   = (const float*)d_in[16];
  const float* b5   = (const float*)d_in[17];
  float* out = (float*)d_out;

  const int nrows = in_sizes[0];        // 262144
  const int grid  = nrows / RPB;        // 4096
  hipLaunchKernelGGL(adain_fused, dim3(grid), dim3(NTHR), 0, stream,
                     x, meta, mw1, mb1, mw2, mb2, mw3, mb3,
                     w1, b1, w2, b2, w3, b3, w4, b4, w5, b5, out);
}

// Round 2
// 355.198 us; speedup vs baseline: 5.2416x; 5.2416x over previous
//
#include <hip/hip_runtime.h>

#define RPB  64     // rows per block
#define NTHR 512    // 8 waves

typedef _Float16 f16;
typedef _Float16 f16x2 __attribute__((ext_vector_type(2)));
typedef _Float16 f16x8 __attribute__((ext_vector_type(8)));
typedef float    f32x4 __attribute__((ext_vector_type(4)));

// ---- workspace layout: weights packed to f16 in B-fragment order ----
// group = 8 f16 = 16 B.  within a matrix (N x K):
//   fb = (n>>4)*(K>>5) + ks ; lane = (b<<4)|(n&15) ; contents W[n][ks*32+b*8 .. +7]
//   flat group = fb*64 + lane
#define G_MW2 1024                 // 128*64/8
#define G_W   2048                 // 128*128/8
#define G_MW3 16384                // 1024*128/8
#define GO_MW2 0
#define GO_W2  (GO_MW2 + G_MW2)
#define GO_W3  (GO_W2 + G_W)
#define GO_W4  (GO_W3 + G_W)
#define GO_MW3 (GO_W4 + G_W)
#define G_TOT  (GO_MW3 + G_MW3)    // 23552 groups
#define WS_BYTES ((size_t)G_TOT * 16)

__global__ void pack_weights(const float* __restrict__ mw2, const float* __restrict__ w2,
                             const float* __restrict__ w3,  const float* __restrict__ w4,
                             const float* __restrict__ mw3, f16x8* __restrict__ ws) {
  int g = blockIdx.x * blockDim.x + threadIdx.x;
  if (g >= G_TOT) return;
  const float* W; int K; int local;
  if (g < GO_W2)       { W = mw2; K = 64;  local = g; }
  else if (g < GO_W3)  { W = w2;  K = 128; local = g - GO_W2; }
  else if (g < GO_W4)  { W = w3;  K = 128; local = g - GO_W3; }
  else if (g < GO_MW3) { W = w4;  K = 128; local = g - GO_W4; }
  else                 { W = mw3; K = 128; local = g - GO_MW3; }
  const int lane = local & 63, fb = local >> 6;
  const int ksteps = K >> 5;
  const int ks = fb % ksteps, n0g = fb / ksteps;
  const int n  = n0g * 16 + (lane & 15);
  const int k0 = ks * 32 + (lane >> 4) * 8;
  const float4* p = (const float4*)(W + (size_t)n * K + k0);
  float4 f0 = p[0], f1 = p[1];
  f16x8 o;
  o[0]=(f16)f0.x; o[1]=(f16)f0.y; o[2]=(f16)f0.z; o[3]=(f16)f0.w;
  o[4]=(f16)f1.x; o[5]=(f16)f1.y; o[6]=(f16)f1.z; o[7]=(f16)f1.w;
  ws[g] = o;
}

// B-fragment load: from packed ws (fast path) or direct fp32 global (fallback)
template<bool WS>
__device__ __forceinline__ f16x8 ldB(const f16x8* __restrict__ wp,
                                     const float* __restrict__ wf,
                                     int K, int n0, int ks, int lane) {
  if constexpr (WS) {
    const int fb = (n0 >> 4) * (K >> 5) + ks;
    return wp[fb * 64 + lane];
  } else {
    const int n  = n0 + (lane & 15);
    const int k0 = ks * 32 + (lane >> 4) * 8;
    const float4* p = (const float4*)(wf + (size_t)n * K + k0);
    float4 f0 = p[0], f1 = p[1];
    f16x8 o;
    o[0]=(f16)f0.x; o[1]=(f16)f0.y; o[2]=(f16)f0.z; o[3]=(f16)f0.w;
    o[4]=(f16)f1.x; o[5]=(f16)f1.y; o[6]=(f16)f1.z; o[7]=(f16)f1.w;
    return o;
  }
}

#define MFMA(a, b, c) __builtin_amdgcn_mfma_f32_16x16x32_f16((a), (b), (c), 0, 0, 0)

template<bool WS>
__global__ __launch_bounds__(NTHR, 1)
void adain_mfma(const float* __restrict__ x,   const float* __restrict__ meta,
                const float* __restrict__ mw1, const float* __restrict__ mb1,
                const float* __restrict__ mw2, const float* __restrict__ mb2,
                const float* __restrict__ mw3, const float* __restrict__ mb3,
                const float* __restrict__ w1,  const float* __restrict__ b1,
                const float* __restrict__ w2,  const float* __restrict__ b2,
                const float* __restrict__ w3,  const float* __restrict__ b3,
                const float* __restrict__ w4,  const float* __restrict__ b4,
                const float* __restrict__ w5,  const float* __restrict__ b5,
                const f16x8* __restrict__ wsp, float* __restrict__ out)
{
  __shared__ float sMeta[RPB][16];     // 4 KB
  __shared__ float sX[RPB];
  __shared__ f16   sH1[RPB][72];       // 9 KB   (pad 64->72: 2-way banks, free)
  __shared__ f16   sH2[RPB][136];      // 17 KB  (pad 128->136)
  __shared__ f16   sY[RPB][136];       // 17 KB
  __shared__ f16   sS[RPB][264];       // 33 KB  (pad 256->264)
  __shared__ float sPre[RPB][132];     // 33 KB  (pad 128->132)

  const int t    = threadIdx.x;
  const int lane = t & 63;
  const int wid  = t >> 6;
  const int r0   = blockIdx.x * RPB;

  const f16x8* mw2p = wsp + GO_MW2;
  const f16x8* w2p  = wsp + GO_W2;
  const f16x8* w3p  = wsp + GO_W3;
  const f16x8* w4p  = wsp + GO_W4;
  const f16x8* mw3p = wsp + GO_MW3;

  // ---- stage metadata + x ----
  for (int i = t; i < RPB * 16; i += NTHR)
    sMeta[i >> 4][i & 15] = meta[(size_t)r0 * 16 + i];
  if (t < RPB) sX[t] = x[r0 + t];
  __syncthreads();

  // ---- h1 = relu(meta @ mw1.T) : (64,16)->(64,64), VALU (K=16) ----
  {
    const int j = t & 63, rg = t >> 6;
    float wr[16];
    const float4* p4 = (const float4*)(mw1 + j * 16);
#pragma unroll
    for (int q = 0; q < 4; ++q) {
      float4 f = p4[q];
      wr[4*q] = f.x; wr[4*q+1] = f.y; wr[4*q+2] = f.z; wr[4*q+3] = f.w;
    }
    const float bj = mb1[j];
#pragma unroll 1
    for (int rr = 0; rr < 8; ++rr) {
      const int r = rg * 8 + rr;
      float acc = bj;
#pragma unroll
      for (int k = 0; k < 16; ++k) acc += wr[k] * sMeta[r][k];
      sH1[r][j] = (f16)fmaxf(acc, 0.0f);
    }
  }
  __syncthreads();

  // per-wave tile geometry: 4 row-stripes x 2 column-halves
  const int rs  = wid >> 1, ch = wid & 1;
  const int rr0 = rs * 16;
  const int arow = rr0 + (lane & 15);
  const int acol = (lane >> 4) * 8;
  const int drow = rr0 + (lane >> 4) * 4;
  const int ncol = lane & 15;

  // ---- h2 = relu(h1 @ mw2.T) : (64,64)->(64,128), MFMA K=64 ----
  {
    f16x8 a0 = *(const f16x8*)&sH1[arow][acol];
    f16x8 a1 = *(const f16x8*)&sH1[arow][32 + acol];
#pragma unroll
    for (int tt = 0; tt < 4; ++tt) {
      const int n0 = ch * 64 + tt * 16;
      f32x4 acc = {0.f, 0.f, 0.f, 0.f};
      f16x8 b0 = ldB<WS>(mw2p, mw2, 64, n0, 0, lane);
      f16x8 b1 = ldB<WS>(mw2p, mw2, 64, n0, 1, lane);
      acc = MFMA(a0, b0, acc);
      acc = MFMA(a1, b1, acc);
      const float bias = mb2[n0 + ncol];
#pragma unroll
      for (int q = 0; q < 4; ++q)
        sH2[drow + q][n0 + ncol] = (f16)fmaxf(acc[q] + bias, 0.0f);
    }
  }
  __syncthreads();

  // ---- 4 AdaIN layers ----
#pragma unroll 1
  for (int l = 0; l < 4; ++l) {
    // (a) style chunk l (MFMA): sS = h2 @ mw3[l*256..].T + mb3
    {
      f16x8 a[4];
#pragma unroll
      for (int ks = 0; ks < 4; ++ks)
        a[ks] = *(const f16x8*)&sH2[arow][ks * 32 + acol];
#pragma unroll
      for (int tt = 0; tt < 8; ++tt) {
        const int nloc = ch * 128 + tt * 16;
        const int ng   = l * 256 + nloc;
        f32x4 acc = {0.f, 0.f, 0.f, 0.f};
#pragma unroll
        for (int ks = 0; ks < 4; ++ks) {
          f16x8 b = ldB<WS>(mw3p, mw3, 128, ng, ks, lane);
          acc = MFMA(a[ks], b, acc);
        }
        const float bias = mb3[ng + ncol];
#pragma unroll
        for (int q = 0; q < 4; ++q)
          sS[drow + q][nloc + ncol] = (f16)(acc[q] + bias);
      }
    }

    // (b) main-chain pre-activation for this layer -> sPre
    if (l == 0) {
      const int c = t & 127, rq = t >> 7;
      const float w1c = w1[c], b1c = b1[c];
#pragma unroll 1
      for (int rr = 0; rr < 16; ++rr) {
        const int r = rq * 16 + rr;
        sPre[r][c] = sX[r] * w1c + b1c;
      }
    } else {
      const float* Wf = (l == 1) ? w2  : (l == 2) ? w3  : w4;
      const f16x8* Wp = (l == 1) ? w2p : (l == 2) ? w3p : w4p;
      const float* Bv = (l == 1) ? b2  : (l == 2) ? b3  : b4;
      f16x8 a[4];
#pragma unroll
      for (int ks = 0; ks < 4; ++ks)
        a[ks] = *(const f16x8*)&sY[arow][ks * 32 + acol];
#pragma unroll
      for (int tt = 0; tt < 4; ++tt) {
        const int n0 = ch * 64 + tt * 16;
        f32x4 acc = {0.f, 0.f, 0.f, 0.f};
#pragma unroll
        for (int ks = 0; ks < 4; ++ks) {
          f16x8 b = ldB<WS>(Wp, Wf, 128, n0, ks, lane);
          acc = MFMA(a[ks], b, acc);
        }
        const float bias = Bv[n0 + ncol];
#pragma unroll
        for (int q = 0; q < 4; ++q)
          sPre[drow + q][n0 + ncol] = acc[q] + bias;
      }
    }
    __syncthreads();

    // (c) adain + lrelu : sPre + sS -> sY
    {
      const int r = t >> 3, j = t & 7;
      float s = 0.0f;
#pragma unroll
      for (int i = 0; i < 16; ++i) s += sPre[r][j + 8 * i];
      s += __shfl_xor(s, 1, 8);
      s += __shfl_xor(s, 2, 8);
      s += __shfl_xor(s, 4, 8);
      const float mu = s * (1.0f / 128.0f);

      float v = 0.0f;
#pragma unroll
      for (int i = 0; i < 16; ++i) {
        const float d = sPre[r][j + 8 * i] - mu;
        v += d * d;
      }
      v += __shfl_xor(v, 1, 8);
      v += __shfl_xor(v, 2, 8);
      v += __shfl_xor(v, 4, 8);
      const float sigma = sqrtf(v * (1.0f / 127.0f)) + 1e-6f;
      const float rsg = 1.0f / sigma;

#pragma unroll
      for (int i = 0; i < 16; ++i) {
        const int k = j + 8 * i;
        f16x2 sb = *(const f16x2*)&sS[r][2 * k];
        const float scale = (float)sb[0];
        const float bias  = (float)sb[1];
        float val = scale * (sPre[r][k] - mu) * rsg + bias;
        val = (val > 0.0f) ? val : 0.01f * val;
        sY[r][k] = (f16)val;
      }
    }
    __syncthreads();
  }

  // ---- out = lrelu(y @ w5.T + b5) ----
  {
    const int r = t >> 3, j = t & 7;
    float s = 0.0f;
#pragma unroll
    for (int i = 0; i < 16; ++i) {
      const int k = j + 8 * i;
      s += (float)sY[r][k] * w5[k];
    }
    s += __shfl_xor(s, 1, 8);
    s += __shfl_xor(s, 2, 8);
    s += __shfl_xor(s, 4, 8);
    if (j == 0) {
      float val = s + b5[0];
      val = (val > 0.0f) ? val : 0.01f * val;
      out[r0 + r] = val;
    }
  }
}

extern "C" void kernel_launch(void* const* d_in, const int* in_sizes, int n_in,
                              void* d_out, int out_size, void* d_ws, size_t ws_size,
                              hipStream_t stream) {
  const float* x    = (const float*)d_in[0];
  const float* meta = (const float*)d_in[1];
  const float* mw1  = (const float*)d_in[2];
  const float* mb1  = (const float*)d_in[3];
  const float* mw2  = (const float*)d_in[4];
  const float* mb2  = (const float*)d_in[5];
  const float* mw3  = (const float*)d_in[6];
  const float* mb3  = (const float*)d_in[7];
  const float* w1   = (const float*)d_in[8];
  const float* b1   = (const float*)d_in[9];
  const float* w2   = (const float*)d_in[10];
  const float* b2   = (const float*)d_in[11];
  const float* w3   = (const float*)d_in[12];
  const float* b3   = (const float*)d_in[13];
  const float* w4   = (const float*)d_in[14];
  const float* b4   = (const float*)d_in[15];
  const float* w5   = (const float*)d_in[16];
  const float* b5   = (const float*)d_in[17];
  float* out = (float*)d_out;

  const int nrows = in_sizes[0];        // 262144
  const int grid  = nrows / RPB;        // 4096

  const bool usews = (ws_size >= WS_BYTES) && (d_ws != nullptr);
  if (usews) {
    f16x8* wsp = (f16x8*)d_ws;
    hipLaunchKernelGGL(pack_weights, dim3((G_TOT + 255) / 256), dim3(256), 0, stream,
                       mw2, w2, w3, w4, mw3, wsp);
    hipLaunchKernelGGL(adain_mfma<true>, dim3(grid), dim3(NTHR), 0, stream,
                       x, meta, mw1, mb1, mw2, mb2, mw3, mb3,
                       w1, b1, w2, b2, w3, b3, w4, b4, w5, b5, wsp, out);
  } else {
    hipLaunchKernelGGL(adain_mfma<false>, dim3(grid), dim3(NTHR), 0, stream,
                       x, meta, mw1, mb1, mw2, mb2, mw3, mb3,
                       w1, b1, w2, b2, w3, b3, w4, b4, w5, b5, (const f16x8*)nullptr, out);
  }
}

// Round 3
// 251.937 us; speedup vs baseline: 7.3899x; 1.4099x over previous
//
#include <hip/hip_runtime.h>

#define RPB  128    // rows per block
#define NTHR 512    // 8 waves: wave = (rs 0..3, ch 0..1), 32 rows x 64 cols each

typedef _Float16 f16;
typedef _Float16 f16x2 __attribute__((ext_vector_type(2)));
typedef _Float16 f16x8 __attribute__((ext_vector_type(8)));
typedef float    f32x4 __attribute__((ext_vector_type(4)));

// ---- workspace layout: weights packed to f16 in B-fragment order ----
// linear matrices (mw2,w2,w3,w4): frag fb=(n>>4)*(K>>5)+ks ; lane=(b<<4)|(n&15)
//   holds W[n][ks*32+b*8 .. +7] ; flat group = fb*64+lane
// mw3 (style, AdaIN-interleaved): frag (l,ch,tt,sb,ks):
//   lane ln -> W row l*256 + 2*(ch*64+tt*16+(ln&15)) + sb ; k0 = ks*32+(ln>>4)*8
#define G_MW2 1024                 // 128*64/8
#define G_W   2048                 // 128*128/8
#define G_MW3 16384                // 1024*128/8
#define GO_MW2 0
#define GO_W2  (GO_MW2 + G_MW2)
#define GO_W3  (GO_W2 + G_W)
#define GO_W4  (GO_W3 + G_W)
#define GO_MW3 (GO_W4 + G_W)
#define G_TOT  (GO_MW3 + G_MW3)    // 23552 groups
#define WS_BYTES ((size_t)G_TOT * 16)

__device__ __forceinline__ f16x8 cvt8(const float* __restrict__ p) {
  const float4* p4 = (const float4*)p;
  float4 f0 = p4[0], f1 = p4[1];
  f16x8 o;
  o[0]=(f16)f0.x; o[1]=(f16)f0.y; o[2]=(f16)f0.z; o[3]=(f16)f0.w;
  o[4]=(f16)f1.x; o[5]=(f16)f1.y; o[6]=(f16)f1.z; o[7]=(f16)f1.w;
  return o;
}

__global__ void pack_weights(const float* __restrict__ mw2, const float* __restrict__ w2,
                             const float* __restrict__ w3,  const float* __restrict__ w4,
                             const float* __restrict__ mw3, f16x8* __restrict__ ws) {
  int g = blockIdx.x * blockDim.x + threadIdx.x;
  if (g >= G_TOT) return;
  if (g < GO_MW3) {                 // linear-packed matrices
    const float* W; int K; int local;
    if (g < GO_W2)       { W = mw2; K = 64;  local = g; }
    else if (g < GO_W3)  { W = w2;  K = 128; local = g - GO_W2; }
    else if (g < GO_W4)  { W = w3;  K = 128; local = g - GO_W3; }
    else                 { W = w4;  K = 128; local = g - GO_W4; }
    const int lane = local & 63, fb = local >> 6;
    const int ksteps = K >> 5;
    const int ks = fb % ksteps, n0g = fb / ksteps;
    const int n  = n0g * 16 + (lane & 15);
    const int k0 = ks * 32 + (lane >> 4) * 8;
    ws[g] = cvt8(W + (size_t)n * K + k0);
  } else {                          // mw3: AdaIN-interleaved
    const int local = g - GO_MW3;
    const int lane = local & 63, fb = local >> 6;   // fb: l(2) ch(1) tt(2) sb(1) ks(2)
    const int ks = fb & 3, sb = (fb >> 2) & 1, tt = (fb >> 3) & 3;
    const int ch = (fb >> 5) & 1, l = fb >> 6;
    const int n  = l * 256 + 2 * (ch * 64 + tt * 16 + (lane & 15)) + sb;
    const int k0 = ks * 32 + (lane >> 4) * 8;
    ws[g] = cvt8(mw3 + (size_t)n * 128 + k0);
  }
}

template<bool WS>
__device__ __forceinline__ f16x8 ldB(const f16x8* __restrict__ wp,
                                     const float* __restrict__ wf,
                                     int K, int n0, int ks, int lane) {
  if constexpr (WS) {
    return wp[((n0 >> 4) * (K >> 5) + ks) * 64 + lane];
  } else {
    const int n  = n0 + (lane & 15);
    const int k0 = ks * 32 + (lane >> 4) * 8;
    return cvt8(wf + (size_t)n * K + k0);
  }
}

template<bool WS>
__device__ __forceinline__ f16x8 ldB3(const f16x8* __restrict__ wp,
                                      const float* __restrict__ wf,
                                      int l, int ch, int tt, int sb, int ks, int lane) {
  if constexpr (WS) {
    const int fb = (((l * 2 + ch) * 4 + tt) * 2 + sb) * 4 + ks;
    return wp[fb * 64 + lane];
  } else {
    const int n  = l * 256 + 2 * (ch * 64 + tt * 16 + (lane & 15)) + sb;
    const int k0 = ks * 32 + (lane >> 4) * 8;
    return cvt8(wf + (size_t)n * 128 + k0);
  }
}

#define MFMA(a, b, c) __builtin_amdgcn_mfma_f32_16x16x32_f16((a), (b), (c), 0, 0, 0)

template<bool WS>
__global__ __launch_bounds__(NTHR, 2)
void adain_mfma(const float* __restrict__ x,   const float* __restrict__ meta,
                const float* __restrict__ mw1, const float* __restrict__ mb1,
                const float* __restrict__ mw2, const float* __restrict__ mb2,
                const float* __restrict__ mw3, const float* __restrict__ mb3,
                const float* __restrict__ w1,  const float* __restrict__ b1,
                const float* __restrict__ w2,  const float* __restrict__ b2,
                const float* __restrict__ w3,  const float* __restrict__ b3,
                const float* __restrict__ w4,  const float* __restrict__ b4,
                const float* __restrict__ w5,  const float* __restrict__ b5,
                const f16x8* __restrict__ wsp, float* __restrict__ out)
{
  __shared__ float  sMeta[RPB][16];   // 8 KB
  __shared__ float  sX[RPB];
  __shared__ f16    sH1[RPB][72];     // 18 KB (pad: 2-way banks, free)
  __shared__ f16    sH2[RPB][136];    // 34 KB
  __shared__ f16    sY[RPB][136];     // 34 KB
  __shared__ float2 sStats[RPB][2];   // 2 KB  (s1,s2) per row per ch-half
  __shared__ float  sOut[RPB][2];     // 1 KB

  const int t    = threadIdx.x;
  const int lane = t & 63;
  const int wid  = t >> 6;
  const int rs   = wid >> 1, ch = wid & 1;
  const int r0   = blockIdx.x * RPB;
  const int ln   = lane & 15;         // fragment n / A-row index
  const int bg   = lane >> 4;         // k-subgroup
  const int acol = bg * 8;
  const int g4   = bg * 4;            // D-row base offset

  // ---- stage metadata + x ----
  ((float4*)&sMeta[0][0])[t] = ((const float4*)(meta + (size_t)r0 * 16))[t];
  if (t < RPB) sX[t] = x[r0 + t];
  __syncthreads();

  // ---- h1 = relu(meta @ mw1.T + mb1) : (128,16)->(128,64), VALU ----
  {
    const int j = t & 63, rg = t >> 6;
    float wr[16];
    const float4* p4 = (const float4*)(mw1 + j * 16);
#pragma unroll
    for (int q = 0; q < 4; ++q) {
      float4 f = p4[q];
      wr[4*q] = f.x; wr[4*q+1] = f.y; wr[4*q+2] = f.z; wr[4*q+3] = f.w;
    }
    const float bj = mb1[j];
#pragma unroll
    for (int rr = 0; rr < 16; ++rr) {
      const int r = rg * 16 + rr;
      float acc = bj;
#pragma unroll
      for (int k = 0; k < 16; ++k) acc += wr[k] * sMeta[r][k];
      sH1[r][j] = (f16)fmaxf(acc, 0.0f);
    }
  }
  __syncthreads();

  // ---- h2 = relu(h1 @ mw2.T + mb2) : MFMA K=64, wave: 32 rows x 64 cols ----
  {
    f16x8 a0[2], a1[2];
#pragma unroll
    for (int p = 0; p < 2; ++p) {
      const int ar = rs * 32 + p * 16 + ln;
      a0[p] = *(const f16x8*)&sH1[ar][acol];
      a1[p] = *(const f16x8*)&sH1[ar][32 + acol];
    }
#pragma unroll
    for (int tt = 0; tt < 4; ++tt) {
      const int n0 = ch * 64 + tt * 16;
      f16x8 b0 = ldB<WS>(wsp + GO_MW2, mw2, 64, n0, 0, lane);
      f16x8 b1 = ldB<WS>(wsp + GO_MW2, mw2, 64, n0, 1, lane);
      const float bias = mb2[n0 + ln];
#pragma unroll
      for (int p = 0; p < 2; ++p) {
        f32x4 acc = {0.f, 0.f, 0.f, 0.f};
        acc = MFMA(a0[p], b0, acc);
        acc = MFMA(a1[p], b1, acc);
        const int dr = rs * 32 + p * 16 + g4;
#pragma unroll
        for (int q = 0; q < 4; ++q)
          sH2[dr + q][n0 + ln] = (f16)fmaxf(acc[q] + bias, 0.0f);
      }
    }
  }
  __syncthreads();

  // ---- 4 AdaIN layers, fully register-resident ----
#pragma unroll 1
  for (int l = 0; l < 4; ++l) {
    // (a) style: scale/bias land in matching lanes via interleaved packing
    f32x4 accS[2][4], accB[2][4];
    {
      f16x8 aH[2][4];
#pragma unroll
      for (int p = 0; p < 2; ++p) {
        const int ar = rs * 32 + p * 16 + ln;
#pragma unroll
        for (int ks = 0; ks < 4; ++ks)
          aH[p][ks] = *(const f16x8*)&sH2[ar][ks * 32 + acol];
      }
#pragma unroll
      for (int tt = 0; tt < 4; ++tt) {
#pragma unroll
        for (int sb = 0; sb < 2; ++sb) {
          f32x4 ac0 = {0.f,0.f,0.f,0.f}, ac1 = {0.f,0.f,0.f,0.f};
#pragma unroll
          for (int ks = 0; ks < 4; ++ks) {
            f16x8 b = ldB3<WS>(wsp + GO_MW3, mw3, l, ch, tt, sb, ks, lane);
            ac0 = MFMA(aH[0][ks], b, ac0);
            ac1 = MFMA(aH[1][ks], b, ac1);
          }
          if (sb == 0) { accS[0][tt] = ac0; accS[1][tt] = ac1; }
          else         { accB[0][tt] = ac0; accB[1][tt] = ac1; }
        }
      }
    }

    // (b) main-chain pre-activation in registers
    f32x4 accM[2][4];
    if (l == 0) {
#pragma unroll
      for (int tt = 0; tt < 4; ++tt) {
        const int c = ch * 64 + tt * 16 + ln;
        const float w1c = w1[c], b1c = b1[c];
#pragma unroll
        for (int p = 0; p < 2; ++p) {
          const int dr = rs * 32 + p * 16 + g4;
#pragma unroll
          for (int q = 0; q < 4; ++q) accM[p][tt][q] = sX[dr + q] * w1c + b1c;
        }
      }
    } else {
      const f16x8* Wp; const float* Wf; const float* Bv;
      if (l == 1)      { Wp = wsp + GO_W2; Wf = w2; Bv = b2; }
      else if (l == 2) { Wp = wsp + GO_W3; Wf = w3; Bv = b3; }
      else             { Wp = wsp + GO_W4; Wf = w4; Bv = b4; }
      f16x8 aY[2][4];
#pragma unroll
      for (int p = 0; p < 2; ++p) {
        const int ar = rs * 32 + p * 16 + ln;
#pragma unroll
        for (int ks = 0; ks < 4; ++ks)
          aY[p][ks] = *(const f16x8*)&sY[ar][ks * 32 + acol];
      }
#pragma unroll
      for (int tt = 0; tt < 4; ++tt) {
        const int n0 = ch * 64 + tt * 16;
        f32x4 ac0 = {0.f,0.f,0.f,0.f}, ac1 = {0.f,0.f,0.f,0.f};
#pragma unroll
        for (int ks = 0; ks < 4; ++ks) {
          f16x8 b = ldB<WS>(Wp, Wf, 128, n0, ks, lane);
          ac0 = MFMA(aY[0][ks], b, ac0);
          ac1 = MFMA(aY[1][ks], b, ac1);
        }
        const float bias = Bv[n0 + ln];
#pragma unroll
        for (int q = 0; q < 4; ++q) { ac0[q] += bias; ac1[q] += bias; }
        accM[0][tt] = ac0; accM[1][tt] = ac1;
      }
    }

    // (c) row stats: shuffle-reduce within 16-lane groups, cross-ch via LDS
#pragma unroll
    for (int p = 0; p < 2; ++p) {
      float s1[4] = {0,0,0,0}, s2[4] = {0,0,0,0};
#pragma unroll
      for (int tt = 0; tt < 4; ++tt)
#pragma unroll
        for (int q = 0; q < 4; ++q) {
          const float v = accM[p][tt][q];
          s1[q] += v; s2[q] += v * v;
        }
#pragma unroll
      for (int m = 1; m < 16; m <<= 1)
#pragma unroll
        for (int q = 0; q < 4; ++q) {
          s1[q] += __shfl_xor(s1[q], m, 64);
          s2[q] += __shfl_xor(s2[q], m, 64);
        }
      if (ln == 0) {
        const int dr = rs * 32 + p * 16 + g4;
#pragma unroll
        for (int q = 0; q < 4; ++q) sStats[dr + q][ch] = make_float2(s1[q], s2[q]);
      }
    }
    __syncthreads();

    float mu[2][4], rsg[2][4];
#pragma unroll
    for (int p = 0; p < 2; ++p) {
      const int dr = rs * 32 + p * 16 + g4;
#pragma unroll
      for (int q = 0; q < 4; ++q) {
        const float2 A = sStats[dr + q][0], Bc = sStats[dr + q][1];
        const float S1 = A.x + Bc.x, S2 = A.y + Bc.y;
        const float m = S1 * (1.0f / 128.0f);
        float var = (S2 - S1 * m) * (1.0f / 127.0f);
        var = fmaxf(var, 0.0f);
        mu[p][q]  = m;
        rsg[p][q] = 1.0f / (sqrtf(var) + 1e-6f);
      }
    }

    // (d) apply adain + lrelu; store sY (layers 0-2) or fuse w5 dot (layer 3)
    if (l < 3) {
#pragma unroll
      for (int tt = 0; tt < 4; ++tt) {
        const int c = ch * 64 + tt * 16 + ln;
        const float2 mb = *(const float2*)(mb3 + l * 256 + 2 * c);
#pragma unroll
        for (int p = 0; p < 2; ++p) {
          const int dr = rs * 32 + p * 16 + g4;
#pragma unroll
          for (int q = 0; q < 4; ++q) {
            const float sc = accS[p][tt][q] + mb.x;
            const float bi = accB[p][tt][q] + mb.y;
            float v = sc * (accM[p][tt][q] - mu[p][q]) * rsg[p][q] + bi;
            v = (v > 0.0f) ? v : 0.01f * v;
            sY[dr + q][c] = (f16)v;
          }
        }
      }
      __syncthreads();
    } else {
      float o[2][4] = {{0,0,0,0},{0,0,0,0}};
#pragma unroll
      for (int tt = 0; tt < 4; ++tt) {
        const int c = ch * 64 + tt * 16 + ln;
        const float2 mb = *(const float2*)(mb3 + l * 256 + 2 * c);
        const float w5c = w5[c];
#pragma unroll
        for (int p = 0; p < 2; ++p)
#pragma unroll
          for (int q = 0; q < 4; ++q) {
            const float sc = accS[p][tt][q] + mb.x;
            const float bi = accB[p][tt][q] + mb.y;
            float v = sc * (accM[p][tt][q] - mu[p][q]) * rsg[p][q] + bi;
            v = (v > 0.0f) ? v : 0.01f * v;
            o[p][q] += v * w5c;
          }
      }
#pragma unroll
      for (int m = 1; m < 16; m <<= 1)
#pragma unroll
        for (int p = 0; p < 2; ++p)
#pragma unroll
          for (int q = 0; q < 4; ++q) o[p][q] += __shfl_xor(o[p][q], m, 64);
      if (ln == 0) {
#pragma unroll
        for (int p = 0; p < 2; ++p) {
          const int dr = rs * 32 + p * 16 + g4;
#pragma unroll
          for (int q = 0; q < 4; ++q) sOut[dr + q][ch] = o[p][q];
        }
      }
      __syncthreads();
      if (t < RPB) {
        float v = sOut[t][0] + sOut[t][1] + b5[0];
        v = (v > 0.0f) ? v : 0.01f * v;
        out[r0 + t] = v;
      }
    }
  }
}

extern "C" void kernel_launch(void* const* d_in, const int* in_sizes, int n_in,
                              void* d_out, int out_size, void* d_ws, size_t ws_size,
                              hipStream_t stream) {
  const float* x    = (const float*)d_in[0];
  const float* meta = (const float*)d_in[1];
  const float* mw1  = (const float*)d_in[2];
  const float* mb1  = (const float*)d_in[3];
  const float* mw2  = (const float*)d_in[4];
  const float* mb2  = (const float*)d_in[5];
  const float* mw3  = (const float*)d_in[6];
  const float* mb3  = (const float*)d_in[7];
  const float* w1   = (const float*)d_in[8];
  const float* b1   = (const float*)d_in[9];
  const float* w2   = (const float*)d_in[10];
  const float* b2   = (const float*)d_in[11];
  const float* w3   = (const float*)d_in[12];
  const float* b3   = (const float*)d_in[13];
  const float* w4   = (const float*)d_in[14];
  const float* b4   = (const float*)d_in[15];
  const float* w5   = (const float*)d_in[16];
  const float* b5   = (const float*)d_in[17];
  float* out = (float*)d_out;

  const int nrows = in_sizes[0];        // 262144
  const int grid  = nrows / RPB;        // 2048

  const bool usews = (ws_size >= WS_BYTES) && (d_ws != nullptr);
  if (usews) {
    f16x8* wsp = (f16x8*)d_ws;
    hipLaunchKernelGGL(pack_weights, dim3((G_TOT + 255) / 256), dim3(256), 0, stream,
                       mw2, w2, w3, w4, mw3, wsp);
    hipLaunchKernelGGL(adain_mfma<true>, dim3(grid), dim3(NTHR), 0, stream,
                       x, meta, mw1, mb1, mw2, mb2, mw3, mb3,
                       w1, b1, w2, b2, w3, b3, w4, b4, w5, b5, wsp, out);
  } else {
    hipLaunchKernelGGL(adain_mfma<false>, dim3(grid), dim3(NTHR), 0, stream,
                       x, meta, mw1, mb1, mw2, mb2, mw3, mb3,
                       w1, b1, w2, b2, w3, b3, w4, b4, w5, b5, (const f16x8*)nullptr, out);
  }
}